// Round 4
// baseline (177.346 us; speedup 1.0000x reference)
//
#include <hip/hip_runtime.h>

#define NEGF 1.0e12f

constexpr int Hdim = 768;
constexpr int SEQ  = 512;

typedef __attribute__((ext_vector_type(8))) short  short8;   // 8 bf16
typedef __attribute__((ext_vector_type(4))) short  short4v;  // 4 bf16
typedef __attribute__((ext_vector_type(4))) float  floatx4;

__device__ inline unsigned short f2bf(float f) {
    union { float f; unsigned u; } v; v.f = f;
    return (unsigned short)((v.u + 0x8000u) >> 16);   // round-half-up, fine at this tol
}

// ---------------------------------------------------------------------------
// K1: fused  t = x @ [W1|W2] + bias  ->  RoPE(start,end) bf16  +  typing f32.
// Grid 256 blocks x 256 thr. Block = 16 rows x 160 cols.
// 4 waves = 2 col-halves (ch: 80 cols) x 2 K-halves (kh: K=384 each).
// K-halves reduced through LDS tacc[2][16][164]; epilogue (RoPE + typing)
// reads tacc. No partial-buffer round-trip, no separate combine kernel.
// ---------------------------------------------------------------------------
__global__ __launch_bounds__(256) void gemm_rope_k(
    const float* __restrict__ x, const float* __restrict__ W1,
    const float* __restrict__ W2, const float* __restrict__ b1,
    const float* __restrict__ b2, unsigned short* __restrict__ startbf,
    unsigned short* __restrict__ endbf, float* __restrict__ tyn,
    float* __restrict__ tym)
{
    __shared__ __align__(16) char smem[28160];
    unsigned short* xs = (unsigned short*)smem;        // [2][16][40] halves
    unsigned short* ws = xs + 2 * 16 * 40;             // [2][160][40] halves
    float* tacc = (float*)smem;                        // [2][16][164] f32 (overlay)

    const int tid  = threadIdx.x;
    const int r0   = blockIdx.x * 16;
    const int wave = tid >> 6;
    const int lane = tid & 63;
    const int quad = lane >> 4;
    const int nl   = lane & 15;
    const int ch   = wave & 1;    // col-half: cols ch*80 .. +79
    const int kh   = wave >> 1;   // K-half:  k  kh*384 .. +383

    floatx4 acc[5];
#pragma unroll
    for (int t = 0; t < 5; t++) acc[t] = (floatx4)(0.0f);

    for (int kt = 0; kt < 384; kt += 32) {
        // stage x: [2 kh][16 rows][32 k] f32 -> bf16 (1 float4 per thread)
        {
            const int khs = tid >> 7;
            const int row = (tid >> 3) & 15;
            const int kq  = (tid & 7) * 4;
            const float* xp = x + (size_t)(r0 + row) * Hdim + khs * 384 + kt + kq;
            float4 v = *(const float4*)xp;
            short4v sv;
            sv[0] = (short)f2bf(v.x); sv[1] = (short)f2bf(v.y);
            sv[2] = (short)f2bf(v.z); sv[3] = (short)f2bf(v.w);
            *(short4v*)(xs + khs * 640 + row * 40 + kq) = sv;
        }
        // stage W transposed -> ws[kh][c][k] (wave-coalesced 256B segments)
        {
            const int khs = tid >> 7;
            const int sub = tid & 127;
            const int kq2 = (sub >> 6) * 8;   // 0 or 8; +16 covers 16,24
#pragma unroll
            for (int g = 0; g < 3; g++) {
                const int c = g * 64 + (sub & 63);
                if (c < 160) {
#pragma unroll
                    for (int h = 0; h < 2; h++) {
                        const int ko = kq2 + h * 16;
                        const int kg = khs * 384 + kt + ko;
                        float f[8];
                        if (c < 128) {
                            const float* wp = W1 + (size_t)kg * 128 + c;
#pragma unroll
                            for (int j = 0; j < 8; j++) f[j] = wp[j * 128];
                        } else {
                            const float* wp = W2 + (size_t)kg * 32 + (c - 128);
#pragma unroll
                            for (int j = 0; j < 8; j++) f[j] = wp[j * 32];
                        }
                        short8 sv;
#pragma unroll
                        for (int j = 0; j < 8; j++) sv[j] = (short)f2bf(f[j]);
                        *(short8*)(ws + khs * 6400 + c * 40 + ko) = sv;
                    }
                }
            }
        }
        __syncthreads();

        short8 af = *(const short8*)(xs + kh * 640 + nl * 40 + quad * 8);
#pragma unroll
        for (int t = 0; t < 5; t++) {
            short8 bf = *(const short8*)(ws + kh * 6400 + (ch * 80 + t * 16 + nl) * 40 + quad * 8);
            acc[t] = __builtin_amdgcn_mfma_f32_16x16x32_bf16(af, bf, acc[t], 0, 0, 0);
        }
        __syncthreads();
    }

    // acc -> tacc  (D layout: row = quad*4 + r, col = t*16 + nl)
#pragma unroll
    for (int t = 0; t < 5; t++)
#pragma unroll
        for (int r = 0; r < 4; r++)
            tacc[kh * (16 * 164) + (quad * 4 + r) * 164 + ch * 80 + t * 16 + nl] = acc[t][r];
    __syncthreads();

    // epilogue: 16 thr/row; thread does rope units {u, u+16} + typing {u, u+16}
    const int row = tid >> 4;
    const int uu  = tid & 15;
    const int R   = r0 + row;
    const int bb  = R >> 9;
    const int s   = R & 511;
    const float* t0p = tacc + row * 164;
    const float* t1p = tacc + 16 * 164 + row * 164;
#pragma unroll
    for (int ii = 0; ii < 2; ii++) {
        const int i = uu + ii * 16;
        floatx4 a  = *(const floatx4*)(t0p + 4 * i);
        floatx4 c  = *(const floatx4*)(t1p + 4 * i);
        floatx4 bv = *(const floatx4*)(b1 + 4 * i);
        float t0 = a[0] + c[0] + bv[0];
        float t1 = a[1] + c[1] + bv[1];
        float t2 = a[2] + c[2] + bv[2];
        float t3 = a[3] + c[3] + bv[3];
        float freq = __powf(10000.0f, -(float)i * (1.0f / 32.0f));
        float ang  = (float)s * freq;
        float sn, cs;
        __sincosf(ang, &sn, &cs);
        // start pair = (t[4i], t[4i+2]) pre-scaled 1/8; end pair = (t[4i+1], t[4i+3])
        float so0 = (t0 * cs - t2 * sn) * 0.125f;
        float so1 = (t2 * cs + t0 * sn) * 0.125f;
        float eo0 = t1 * cs - t3 * sn;
        float eo1 = t3 * cs + t1 * sn;
        ushort2 sp2; sp2.x = f2bf(so0); sp2.y = f2bf(so1);
        ushort2 ep2; ep2.x = f2bf(eo0); ep2.y = f2bf(eo1);
        *(ushort2*)(startbf + (size_t)R * 64 + 2 * i) = sp2;
        *(ushort2*)(endbf   + (size_t)R * 64 + 2 * i) = ep2;
    }
#pragma unroll
    for (int jj = 0; jj < 2; jj++) {
        const int j = uu + jj * 16;
        float t = t0p[128 + j] + t1p[128 + j] + b2[j];
        float v = t * 0.5f;
        const int l = j >> 1;
        if ((j & 1) == 0) tyn[((size_t)bb * 16 + l) * SEQ + s] = v;
        else              tym[((size_t)bb * 16 + l) * SEQ + s] = v;
    }
}

// ---------------------------------------------------------------------------
// K2: fused span + broadcast. Grid (32 m-strips, 2 l-halves, 8 b) x 256 thr.
// Phase 1: span strip (16 m x 512 n) via MFMA; A/B frags loaded DIRECTLY from
// global (L2-hot: 64B/row segments), no staging LDS; sub-diagonal tiles
// skipped (exact: |span+typ| << ulp(1e12)/2 absorbs identically).
// Phase 2: one LDS bounce of the span strip, then coalesced broadcast over
// 8 l-planes: each float4 store = 4 segments x 256 B.
// Masks+tril folded into per-element FMA constants (fp32-exact).
// ---------------------------------------------------------------------------
__global__ __launch_bounds__(256, 2) void entity_fused_k(
    const unsigned short* __restrict__ startbf, const unsigned short* __restrict__ endbf,
    const float* __restrict__ tyn, const float* __restrict__ tym,
    const int* __restrict__ amask, float* __restrict__ out)
{
    __shared__ __align__(16) float span_s[16 * 516];   // stride 516: conflict-spread
    __shared__ __align__(16) float tyn_s[8 * SEQ];
    __shared__ float tym_s[8 * 16];

    const int tid  = threadIdx.x;
    const int m0   = blockIdx.x * 16;
    const int lh   = blockIdx.y;
    const int b    = blockIdx.z;
    const int wave = tid >> 6;
    const int lane = tid & 63;
    const int quad = lane >> 4;
    const int nl   = lane & 15;

    // A-frags: start rows m0..m0+15 (row=nl, k-octet=quad; k 0..31 and 32..63)
    const unsigned short* ap = startbf + ((size_t)(b * SEQ + m0 + nl)) * 64 + quad * 8;
    short8 a0 = *(const short8*)ap;
    short8 a1 = *(const short8*)(ap + 32);

    floatx4 acc[8];
#pragma unroll
    for (int t = 0; t < 8; t++) acc[t] = (floatx4)(0.0f);
#pragma unroll
    for (int t = 0; t < 8; t++) {
        if (wave * 128 + t * 16 + 15 >= m0) {   // skip fully-sub-diagonal tiles
            const unsigned short* ep =
                endbf + ((size_t)(b * SEQ + wave * 128 + t * 16 + nl)) * 64 + quad * 8;
            short8 bf0 = *(const short8*)ep;
            short8 bf1 = *(const short8*)(ep + 32);
            acc[t] = __builtin_amdgcn_mfma_f32_16x16x32_bf16(a0, bf0, acc[t], 0, 0, 0);
            acc[t] = __builtin_amdgcn_mfma_f32_16x16x32_bf16(a1, bf1, acc[t], 0, 0, 0);
        }
    }

    // stage tyn/tym for this l-half
    {
        const floatx4* src = (const floatx4*)(tyn + ((size_t)b * 16 + lh * 8) * SEQ);
        for (int t = tid; t < 8 * SEQ / 4; t += 256) ((floatx4*)tyn_s)[t] = src[t];
        if (tid < 128) {
            const int l = tid >> 4, r = tid & 15;
            tym_s[tid] = tym[((size_t)b * 16 + lh * 8 + l) * SEQ + m0 + r];
        }
    }
    // span -> LDS (D layout: m-local = quad*4+r, n = wave*128 + t*16 + nl)
#pragma unroll
    for (int t = 0; t < 8; t++)
#pragma unroll
        for (int r = 0; r < 4; r++)
            span_s[(quad * 4 + r) * 516 + wave * 128 + t * 16 + nl] = acc[t][r];
    __syncthreads();

    // broadcast: thread = (row = tid>>4, 32 cols = uu*4 + q*64)
    const int row = tid >> 4;
    const int uu  = tid & 15;
    const int m   = m0 + row;
    const float mr   = (float)amask[b * SEQ + m];
    const float radd = -NEGF * (1.0f - mr);

    floatx4 spanz[8], mcv[8], caddv[8];
#pragma unroll
    for (int q = 0; q < 8; q++) {
        spanz[q] = *(const floatx4*)(span_s + row * 516 + uu * 4 + q * 64);
        const int4 mk = *(const int4*)(amask + b * SEQ + uu * 4 + q * 64);
        const int mki[4] = {mk.x, mk.y, mk.z, mk.w};
#pragma unroll
        for (int e = 0; e < 4; e++) {
            const int n = uu * 4 + q * 64 + e;
            float mc = (float)mki[e];
            mcv[q][e] = mc;
            float ca = -NEGF * (1.0f - mc);
            caddv[q][e] = (n < m) ? (ca - NEGF) : ca;   // fold tril (exact)
        }
    }

    for (int l = 0; l < 8; l++) {
        const float tm = tym_s[l * 16 + row];
        float* orow = out + (((size_t)(b * 16 + lh * 8 + l)) * SEQ + m) * SEQ;
#pragma unroll
        for (int q = 0; q < 8; q++) {
            floatx4 t4 = *(const floatx4*)(tyn_s + l * SEQ + uu * 4 + q * 64);
            floatx4 v;
#pragma unroll
            for (int e = 0; e < 4; e++) {
                float xv = spanz[q][e] + t4[e] + tm;
                xv = xv * mr + radd;
                xv = xv * mcv[q][e] + caddv[q][e];
                v[e] = xv;
            }
            *(floatx4*)(orow + uu * 4 + q * 64) = v;
        }
    }
}

// ---------------------------------------------------------------------------
extern "C" void kernel_launch(void* const* d_in, const int* in_sizes, int n_in,
                              void* d_out, int out_size, void* d_ws, size_t ws_size,
                              hipStream_t stream) {
    const float* x     = (const float*)d_in[0];
    const float* W1    = (const float*)d_in[1];
    const float* b1    = (const float*)d_in[2];
    const float* W2    = (const float*)d_in[3];
    const float* b2    = (const float*)d_in[4];
    const int*   amask = (const int*)d_in[5];
    float* out = (float*)d_out;

    char* base = (char*)d_ws;
    unsigned short* startbf = (unsigned short*)base;                 // 4096*64*2 = 512 KB
    unsigned short* endbf   = (unsigned short*)(base + 524288);      // 512 KB
    float*          tyn     = (float*)(base + 1048576);              // 128*512*4 = 256 KB
    float*          tym     = (float*)(base + 1048576 + 262144);     // 256 KB

    hipLaunchKernelGGL(gemm_rope_k, dim3(256), dim3(256), 0, stream,
                       x, W1, W2, b1, b2, startbf, endbf, tyn, tym);
    hipLaunchKernelGGL(entity_fused_k, dim3(32, 2, 8), dim3(256), 0, stream,
                       startbf, endbf, tyn, tym, amask, out);
}

// Round 5
// 170.660 us; speedup vs baseline: 1.0392x; 1.0392x over previous
//
#include <hip/hip_runtime.h>

#define NEGF 1.0e12f

constexpr int Hdim = 768;
constexpr int NC   = 160;   // 128 (W1) + 32 (W2) output columns
constexpr int ROWS = 4096;  // B*S
constexpr int SEQ  = 512;
constexpr int KSPLIT = 4;   // K chunks of 192

typedef __attribute__((ext_vector_type(8))) short  short8;   // 8 bf16
typedef __attribute__((ext_vector_type(4))) float  floatx4;

__device__ inline unsigned short f2bf(float f) {
    union { float f; unsigned u; } v; v.f = f;
    return (unsigned short)((v.u + 0x8000u) >> 16);   // round-half-up, fine at this tol
}

// ---------------------------------------------------------------------------
// Kernel A: partial[kc] = x @ [W1|W2] over K-chunk kc, bf16 MFMA 16x16x32.
// (v1 verbatim — proven absmax 0.0156)
// ---------------------------------------------------------------------------
__global__ __launch_bounds__(256) void gemm_mfma_k(
    const float* __restrict__ x, const float* __restrict__ W1,
    const float* __restrict__ W2, float* __restrict__ partial)
{
    __shared__ __align__(16) unsigned short xs[64 * 40];
    __shared__ __align__(16) unsigned short ws[NC * 40];

    const int tid  = threadIdx.x;
    const int wave = tid >> 6;
    const int lane = tid & 63;
    const int quad = lane >> 4;
    const int nl   = lane & 15;
    const int r0   = blockIdx.x * 64;
    const int k0   = blockIdx.y * 192;

    floatx4 acc[10];
#pragma unroll
    for (int t = 0; t < 10; t++) acc[t] = (floatx4)(0.0f);

    for (int kt = 0; kt < 192; kt += 32) {
        const int kb = k0 + kt;
        {
            const int row = tid >> 2;
            const int kq  = (tid & 3) * 8;
            const float* xp = x + (size_t)(r0 + row) * Hdim + kb + kq;
            float4 v0 = *(const float4*)xp;
            float4 v1 = *(const float4*)(xp + 4);
            short8 sv;
            sv[0] = (short)f2bf(v0.x); sv[1] = (short)f2bf(v0.y);
            sv[2] = (short)f2bf(v0.z); sv[3] = (short)f2bf(v0.w);
            sv[4] = (short)f2bf(v1.x); sv[5] = (short)f2bf(v1.y);
            sv[6] = (short)f2bf(v1.z); sv[7] = (short)f2bf(v1.w);
            *(short8*)(xs + row * 40 + kq) = sv;
        }
#pragma unroll
        for (int g = 0; g < 3; g++) {
            const int c   = g * 64 + (tid & 63);
            const int kq2 = (tid >> 6) * 8;
            if (c < NC) {
                float f[8];
                if (c < 128) {
                    const float* wp = W1 + (size_t)(kb + kq2) * 128 + c;
#pragma unroll
                    for (int j = 0; j < 8; j++) f[j] = wp[j * 128];
                } else {
                    const float* wp = W2 + (size_t)(kb + kq2) * 32 + (c - 128);
#pragma unroll
                    for (int j = 0; j < 8; j++) f[j] = wp[j * 32];
                }
                short8 sv;
#pragma unroll
                for (int j = 0; j < 8; j++) sv[j] = (short)f2bf(f[j]);
                *(short8*)(ws + c * 40 + kq2) = sv;
            }
        }
        __syncthreads();

        short8 af = *(const short8*)(xs + (wave * 16 + nl) * 40 + quad * 8);
#pragma unroll
        for (int t = 0; t < 10; t++) {
            short8 bf = *(const short8*)(ws + (t * 16 + nl) * 40 + quad * 8);
            acc[t] = __builtin_amdgcn_mfma_f32_16x16x32_bf16(af, bf, acc[t], 0, 0, 0);
        }
        __syncthreads();
    }

    float* pout = partial + (size_t)blockIdx.y * ROWS * NC;
#pragma unroll
    for (int t = 0; t < 10; t++) {
#pragma unroll
        for (int r = 0; r < 4; r++) {
            pout[(size_t)(r0 + wave * 16 + quad * 4 + r) * NC + t * 16 + nl] = acc[t][r];
        }
    }
}

// ---------------------------------------------------------------------------
// Kernel B: combine 4 K-partials + bias, RoPE, emit bf16 start/end
// (v1 verbatim — proven absmax 0.0156)
// ---------------------------------------------------------------------------
__global__ __launch_bounds__(256) void combine_rope_k(
    const float* __restrict__ partial, const float* __restrict__ b1,
    const float* __restrict__ b2, unsigned short* __restrict__ startbf,
    unsigned short* __restrict__ endbf, float* __restrict__ tyn,
    float* __restrict__ tym)
{
    const int tid = threadIdx.x;
    const int row = blockIdx.x * 4 + (tid >> 6);
    const int u   = tid & 63;
    const int b   = row >> 9;
    const int s   = row & 511;
    const float* p0 = partial + (size_t)row * NC;
    const size_t cstride = (size_t)ROWS * NC;

    if (u < 32) {
        const int i = u;
        float4 a0 = *(const float4*)(p0 + 4 * i);
        float4 a1 = *(const float4*)(p0 + cstride + 4 * i);
        float4 a2 = *(const float4*)(p0 + 2 * cstride + 4 * i);
        float4 a3 = *(const float4*)(p0 + 3 * cstride + 4 * i);
        float t0 = a0.x + a1.x + a2.x + a3.x + b1[4 * i + 0];
        float t1 = a0.y + a1.y + a2.y + a3.y + b1[4 * i + 1];
        float t2 = a0.z + a1.z + a2.z + a3.z + b1[4 * i + 2];
        float t3 = a0.w + a1.w + a2.w + a3.w + b1[4 * i + 3];
        float freq = __powf(10000.0f, -(float)i * (1.0f / 32.0f));
        float ang  = (float)s * freq;
        float sn, cs;
        __sincosf(ang, &sn, &cs);
        float so0 = (t0 * cs - t2 * sn) * 0.125f;
        float so1 = (t2 * cs + t0 * sn) * 0.125f;
        float eo0 = t1 * cs - t3 * sn;
        float eo1 = t3 * cs + t1 * sn;
        ushort2 sp; sp.x = f2bf(so0); sp.y = f2bf(so1);
        ushort2 ep; ep.x = f2bf(eo0); ep.y = f2bf(eo1);
        *(ushort2*)(startbf + (size_t)row * 64 + 2 * i) = sp;
        *(ushort2*)(endbf   + (size_t)row * 64 + 2 * i) = ep;
    } else {
        const int j = u - 32;
        float t = p0[128 + j] + p0[cstride + 128 + j] + p0[2 * cstride + 128 + j]
                + p0[3 * cstride + 128 + j] + b2[j];
        float v = t * 0.5f;
        const int l = j >> 1;
        if ((j & 1) == 0) tyn[((size_t)b * 16 + l) * SEQ + s] = v;
        else              tym[((size_t)b * 16 + l) * SEQ + s] = v;
    }
}

// ---------------------------------------------------------------------------
// Kernel C: fused span + broadcast (v4-K2, launch_bounds fixed to avoid spill).
// Grid (32 m-strips, 2 l-halves, 8 b) x 256 thr.
// Phase 1: span strip (16 m x 512 n) via MFMA; A/B frags direct from global
// (L2-hot); fully-sub-diagonal 16-col tiles skipped (exact: absorbed by -1e12).
// Phase 2: LDS bounce of the span strip, then coalesced broadcast over 8
// l-planes: each float4 store = 4 segments x 256 B. Masks+tril folded into
// per-element FMA constants (fp32-exact, fma(x,1,-1e12) rounds once).
// ---------------------------------------------------------------------------
__global__ __launch_bounds__(256) void entity_fused_k(
    const unsigned short* __restrict__ startbf, const unsigned short* __restrict__ endbf,
    const float* __restrict__ tyn, const float* __restrict__ tym,
    const int* __restrict__ amask, float* __restrict__ out)
{
    __shared__ __align__(16) float span_s[16 * 516];   // stride 516: conflict-spread
    __shared__ __align__(16) float tyn_s[8 * SEQ];
    __shared__ float tym_s[8 * 16];

    const int tid  = threadIdx.x;
    const int m0   = blockIdx.x * 16;
    const int lh   = blockIdx.y;
    const int b    = blockIdx.z;
    const int wave = tid >> 6;
    const int lane = tid & 63;
    const int quad = lane >> 4;
    const int nl   = lane & 15;

    // A-frags: start rows m0..m0+15 (row=nl, k = quad*8 + j; and +32)
    const unsigned short* ap = startbf + ((size_t)(b * SEQ + m0 + nl)) * 64 + quad * 8;
    short8 a0 = *(const short8*)ap;
    short8 a1 = *(const short8*)(ap + 32);

    floatx4 acc[8];
#pragma unroll
    for (int t = 0; t < 8; t++) acc[t] = (floatx4)(0.0f);
#pragma unroll
    for (int t = 0; t < 8; t++) {
        if (wave * 128 + t * 16 + 15 >= m0) {   // skip fully-sub-diagonal tiles
            const unsigned short* ep =
                endbf + ((size_t)(b * SEQ + wave * 128 + t * 16 + nl)) * 64 + quad * 8;
            short8 bf0 = *(const short8*)ep;
            short8 bf1 = *(const short8*)(ep + 32);
            acc[t] = __builtin_amdgcn_mfma_f32_16x16x32_bf16(a0, bf0, acc[t], 0, 0, 0);
            acc[t] = __builtin_amdgcn_mfma_f32_16x16x32_bf16(a1, bf1, acc[t], 0, 0, 0);
        }
    }

    // stage tyn/tym for this l-half
    {
        const floatx4* src = (const floatx4*)(tyn + ((size_t)b * 16 + lh * 8) * SEQ);
        for (int t = tid; t < 8 * SEQ / 4; t += 256) ((floatx4*)tyn_s)[t] = src[t];
        if (tid < 128) {
            const int l = tid >> 4, r = tid & 15;
            tym_s[tid] = tym[((size_t)b * 16 + lh * 8 + l) * SEQ + m0 + r];
        }
    }
    // span -> LDS (D layout: m-local = quad*4+r, n = wave*128 + t*16 + nl)
#pragma unroll
    for (int t = 0; t < 8; t++)
#pragma unroll
        for (int r = 0; r < 4; r++)
            span_s[(quad * 4 + r) * 516 + wave * 128 + t * 16 + nl] = acc[t][r];
    __syncthreads();

    // broadcast: thread = (row = tid>>4, 32 cols = uu*4 + q*64)
    const int row = tid >> 4;
    const int uu  = tid & 15;
    const int m   = m0 + row;
    const float mr   = (float)amask[b * SEQ + m];
    const float radd = -NEGF * (1.0f - mr);

    floatx4 spanz[8], mcv[8], caddv[8];
#pragma unroll
    for (int q = 0; q < 8; q++) {
        spanz[q] = *(const floatx4*)(span_s + row * 516 + uu * 4 + q * 64);
        const int4 mk = *(const int4*)(amask + b * SEQ + uu * 4 + q * 64);
        const int mki[4] = {mk.x, mk.y, mk.z, mk.w};
#pragma unroll
        for (int e = 0; e < 4; e++) {
            const int n = uu * 4 + q * 64 + e;
            float mc = (float)mki[e];
            mcv[q][e] = mc;
            float ca = -NEGF * (1.0f - mc);
            caddv[q][e] = (n < m) ? (ca - NEGF) : ca;   // fold tril (exact)
        }
    }

    for (int l = 0; l < 8; l++) {
        const float tm = tym_s[l * 16 + row];
        float* orow = out + (((size_t)(b * 16 + lh * 8 + l)) * SEQ + m) * SEQ;
#pragma unroll
        for (int q = 0; q < 8; q++) {
            floatx4 t4 = *(const floatx4*)(tyn_s + l * SEQ + uu * 4 + q * 64);
            floatx4 v;
#pragma unroll
            for (int e = 0; e < 4; e++) {
                float xv = spanz[q][e] + t4[e] + tm;
                xv = xv * mr + radd;
                xv = xv * mcv[q][e] + caddv[q][e];
                v[e] = xv;
            }
            *(floatx4*)(orow + uu * 4 + q * 64) = v;
        }
    }
}

// ---------------------------------------------------------------------------
extern "C" void kernel_launch(void* const* d_in, const int* in_sizes, int n_in,
                              void* d_out, int out_size, void* d_ws, size_t ws_size,
                              hipStream_t stream) {
    const float* x     = (const float*)d_in[0];
    const float* W1    = (const float*)d_in[1];
    const float* b1    = (const float*)d_in[2];
    const float* W2    = (const float*)d_in[3];
    const float* b2    = (const float*)d_in[4];
    const int*   amask = (const int*)d_in[5];
    float* out = (float*)d_out;

    char* base = (char*)d_ws;
    float*          partial = (float*)base;                                 // 4*4096*160*4 B
    unsigned short* startbf = (unsigned short*)(base + 10485760);           // 4096*64*2 B
    unsigned short* endbf   = (unsigned short*)(base + 10485760 + 524288);
    float*          tyn     = (float*)(base + 10485760 + 2 * 524288);       // 8*16*512*4 B
    float*          tym     = (float*)(base + 10485760 + 2 * 524288 + 262144);

    hipLaunchKernelGGL(gemm_mfma_k, dim3(64, KSPLIT), dim3(256), 0, stream,
                       x, W1, W2, partial);
    hipLaunchKernelGGL(combine_rope_k, dim3(ROWS / 4), dim3(256), 0, stream,
                       partial, b1, b2, startbf, endbf, tyn, tym);
    hipLaunchKernelGGL(entity_fused_k, dim3(32, 2, 8), dim3(256), 0, stream,
                       startbf, endbf, tyn, tym, amask, out);
}